// Round 1
// 431.423 us; speedup vs baseline: 1.0055x; 1.0055x over previous
//
#include <hip/hip_runtime.h>

// Welford running mean/variance over batch dim.
// x: (B=256, C=64, H=64, W=64) fp32.  N = C*H*W = 262144 neurons.
// Reference recurrence per sample b (n starts at n0):
//   nn += (x_b != 0)
//   old_m = m; m += (x_b - m) / (n0 + b + 1); s += (x_b - m) * (x_b - old_m)
// Outputs concatenated flat in d_out (float32):
//   [0, B*N)            : x passthrough
//   [B*N, B*N+N)        : m
//   [+N)                : s
//   [+N)                : nn (int counts written as float — exactly representable)
//   [+1)                : n  (= n0 + B, as float)
//
// V2: latency/occupancy fix. float2 per thread (512 blocks -> 2 blocks/CU,
// 8 waves/CU instead of 4 waves/CU) + explicit 8-deep load groups with
// double buffering so ~4KB/wave of reads are in flight before any store
// enters the vmcnt queue. Arithmetic identical to V1 (absmax was 0.0).

constexpr int kB = 256;
constexpr int kN = 64 * 64 * 64; // 262144
constexpr int kBlock = 256;
constexpr int kG = 8;            // load-group depth (in-flight loads per wave)

typedef float f32x2 __attribute__((ext_vector_type(2)));

__global__ __launch_bounds__(kBlock) void welford_fused(
    const float* __restrict__ x,
    const float* __restrict__ m_in,
    const float* __restrict__ s_in,
    const int*   __restrict__ nn_in,
    const int*   __restrict__ n0_in,
    float* __restrict__ out)
{
    const int j2 = blockIdx.x * blockDim.x + threadIdx.x; // float2 group index
    const int j  = j2 * 2;
    if (j >= kN) return;

    float* out_x  = out;
    float* out_m  = out + (size_t)kB * kN;
    float* out_s  = out_m + kN;
    float* out_nn = out_s + kN;
    float* out_n  = out_nn + kN;

    f32x2 m = *(const f32x2*)(m_in + j);
    f32x2 s = *(const f32x2*)(s_in + j);
    const int2 nni = *(const int2*)(nn_in + j);
    const int n0 = n0_in[0]; // wave-uniform

    f32x2 nn;
    nn.x = (float)nni.x;
    nn.y = (float)nni.y;

    f32x2 va[kG], vb[kG];

    // Prologue: fill buffer A with samples [0, kG)
#pragma unroll
    for (int u = 0; u < kG; ++u)
        va[u] = __builtin_nontemporal_load((const f32x2*)(x + (size_t)u * kN + j));

    // Main loop: 2*kG samples per iteration; while processing/storing one
    // group, the other group's loads are already in flight.
    for (int b0 = 0; b0 < kB; b0 += 2 * kG) {
        // Issue loads for group B (samples [b0+kG, b0+2kG))
#pragma unroll
        for (int u = 0; u < kG; ++u)
            vb[u] = __builtin_nontemporal_load(
                (const f32x2*)(x + (size_t)(b0 + kG + u) * kN + j));

        // Process + store group A (samples [b0, b0+kG))
#pragma unroll
        for (int u = 0; u < kG; ++u) {
            const int b = b0 + u;
            const f32x2 v = va[u];
            __builtin_nontemporal_store(v, (f32x2*)(out_x + (size_t)b * kN + j));
            const float inv = 1.0f / (float)(n0 + b + 1);

            nn.x += (v.x != 0.0f) ? 1.0f : 0.0f;
            float om = m.x;
            m.x = om + (v.x - om) * inv;
            s.x += (v.x - m.x) * (v.x - om);

            nn.y += (v.y != 0.0f) ? 1.0f : 0.0f;
            om = m.y;
            m.y = om + (v.y - om) * inv;
            s.y += (v.y - m.y) * (v.y - om);
        }

        // Refill group A for the NEXT iteration (samples [b0+2kG, b0+3kG))
        if (b0 + 2 * kG < kB) {
#pragma unroll
            for (int u = 0; u < kG; ++u)
                va[u] = __builtin_nontemporal_load(
                    (const f32x2*)(x + (size_t)(b0 + 2 * kG + u) * kN + j));
        }

        // Process + store group B (samples [b0+kG, b0+2kG))
#pragma unroll
        for (int u = 0; u < kG; ++u) {
            const int b = b0 + kG + u;
            const f32x2 v = vb[u];
            __builtin_nontemporal_store(v, (f32x2*)(out_x + (size_t)b * kN + j));
            const float inv = 1.0f / (float)(n0 + b + 1);

            nn.x += (v.x != 0.0f) ? 1.0f : 0.0f;
            float om = m.x;
            m.x = om + (v.x - om) * inv;
            s.x += (v.x - m.x) * (v.x - om);

            nn.y += (v.y != 0.0f) ? 1.0f : 0.0f;
            om = m.y;
            m.y = om + (v.y - om) * inv;
            s.y += (v.y - m.y) * (v.y - om);
        }
    }

    *(f32x2*)(out_m  + j) = m;
    *(f32x2*)(out_s  + j) = s;
    *(f32x2*)(out_nn + j) = nn;
    if (j2 == 0) out_n[0] = (float)(n0 + kB);
}

extern "C" void kernel_launch(void* const* d_in, const int* in_sizes, int n_in,
                              void* d_out, int out_size, void* d_ws, size_t ws_size,
                              hipStream_t stream) {
    const float* x     = (const float*)d_in[0];
    const float* m_in  = (const float*)d_in[1];
    const float* s_in  = (const float*)d_in[2];
    const int*   nn_in = (const int*)d_in[3];
    const int*   n0_in = (const int*)d_in[4];
    float* out = (float*)d_out;

    const int threads = kN / 2;                  // 131072
    dim3 grid(threads / kBlock), block(kBlock);  // 512 blocks -> 2 blocks/CU
    welford_fused<<<grid, block, 0, stream>>>(x, m_in, s_in, nn_in, n0_in, out);
}